// Round 5
// baseline (214.533 us; speedup 1.0000x reference)
//
#include <hip/hip_runtime.h>

#define BB 2
#define HH 16
#define TT 2048
#define DD 1024
#define DH 64

typedef _Float16 half8 __attribute__((ext_vector_type(8)));
typedef _Float16 half4v __attribute__((ext_vector_type(4)));
typedef float f32x4 __attribute__((ext_vector_type(4)));

#define GLOAD(g, l)                                                        \
    __builtin_amdgcn_global_load_lds(                                      \
        (const __attribute__((address_space(1))) unsigned int*)(g),        \
        (__attribute__((address_space(3))) unsigned int*)(l), 16, 0, 0)

// ---------------------------------------------------------------------------
// Fused convert kernel: 1 launch instead of 3.
//   blocks [0,2048):    x fp32 -> fp16
//   blocks [2048,2816): W_{Q,K,V}[h][d][e] -> Wt[(m*1024+h*64+e)][d]
//   blocks [2816,3072): W_output [he][d] -> Wot[d][he]
// ---------------------------------------------------------------------------
__global__ __launch_bounds__(256) void cvt_all_kernel(
    const float* __restrict__ x,
    const float* __restrict__ Wq, const float* __restrict__ Wk,
    const float* __restrict__ Wv, const float* __restrict__ Wo,
    _Float16* __restrict__ xh, _Float16* __restrict__ Wt,
    _Float16* __restrict__ Wot)
{
    const int bid = blockIdx.x;
    const int tid = threadIdx.x;
    __shared__ float ts[64][68];

    if (bid < 2048) {
        size_t i = ((size_t)bid * 256 + tid) * 8;
        float4 a = *(const float4*)&x[i];
        float4 b = *(const float4*)&x[i + 4];
        half8 o;
        o[0] = (_Float16)a.x; o[1] = (_Float16)a.y; o[2] = (_Float16)a.z; o[3] = (_Float16)a.w;
        o[4] = (_Float16)b.x; o[5] = (_Float16)b.y; o[6] = (_Float16)b.z; o[7] = (_Float16)b.w;
        *(half8*)&xh[i] = o;
        return;
    }

    if (bid < 2816) {
        const int r = bid - 2048;
        const int d0 = (r & 15) * 64;
        const int h = (r >> 4) & 15;
        const int m = r >> 8;
        const float* __restrict__ W = (m == 0) ? Wq : (m == 1) ? Wk : Wv;

        const int dr = tid >> 2, ec = (tid & 3) * 16;
        const float* p = W + ((size_t)h * DD + d0 + dr) * DH + ec;
        *(float4*)&ts[dr][ec + 0]  = *(const float4*)(p + 0);
        *(float4*)&ts[dr][ec + 4]  = *(const float4*)(p + 4);
        *(float4*)&ts[dr][ec + 8]  = *(const float4*)(p + 8);
        *(float4*)&ts[dr][ec + 12] = *(const float4*)(p + 12);
        __syncthreads();

        const int er = tid >> 2, dc = (tid & 3) * 16;
        size_t obase = ((size_t)m * 1024 + h * 64 + er) * 1024 + d0 + dc;
        half8 o;
#pragma unroll
        for (int j = 0; j < 8; ++j) o[j] = (_Float16)ts[dc + j][er];
        *(half8*)&Wt[obase] = o;
#pragma unroll
        for (int j = 0; j < 8; ++j) o[j] = (_Float16)ts[dc + 8 + j][er];
        *(half8*)&Wt[obase + 8] = o;
        return;
    }

    {
        const int r = bid - 2816;
        const int r0 = (r & 15) * 64;   // he
        const int c0 = (r >> 4) * 64;   // d

        const int rr = tid >> 2, cc = (tid & 3) * 16;
        const float* p = Wo + (size_t)(r0 + rr) * 1024 + c0 + cc;
        *(float4*)&ts[rr][cc + 0]  = *(const float4*)(p + 0);
        *(float4*)&ts[rr][cc + 4]  = *(const float4*)(p + 4);
        *(float4*)&ts[rr][cc + 8]  = *(const float4*)(p + 8);
        *(float4*)&ts[rr][cc + 12] = *(const float4*)(p + 12);
        __syncthreads();

        const int er = tid >> 2, dc = (tid & 3) * 16;
        size_t obase = (size_t)(c0 + er) * 1024 + r0 + dc;
        half8 o;
#pragma unroll
        for (int j = 0; j < 8; ++j) o[j] = (_Float16)ts[dc + j][er];
        *(half8*)&Wot[obase] = o;
#pragma unroll
        for (int j = 0; j < 8; ++j) o[j] = (_Float16)ts[dc + 8 + j][er];
        *(half8*)&Wot[obase + 8] = o;
    }
}

// ---------------------------------------------------------------------------
// MFMA GEMM core (m97 recipe): 128x128 tile, BK=64, global_load_lds w=16,
// XOR-swizzled unpadded LDS.
// ---------------------------------------------------------------------------
#define GEMM_MAIN(Aptr, Bptr, lda, ldb, KDIM)                                   \
    __shared__ _Float16 As[128 * 64];                                           \
    __shared__ _Float16 Bs[128 * 64];                                           \
    const int tid = threadIdx.x;                                                \
    const int wave = tid >> 6, lane = tid & 63;                                 \
    const int quad = lane >> 4, l15 = lane & 15;                                \
    const int rowBase = blockIdx.x * 128;                                       \
    const int colBase = blockIdx.y * 128;                                       \
    const int wr = (wave >> 1) * 64, wc = (wave & 1) * 64;                      \
    f32x4 acc[4][4];                                                            \
    _Pragma("unroll") for (int sm = 0; sm < 4; ++sm)                            \
        _Pragma("unroll") for (int sn = 0; sn < 4; ++sn)                        \
            acc[sm][sn] = f32x4{0.f, 0.f, 0.f, 0.f};                            \
    for (int k0 = 0; k0 < (KDIM); k0 += 64) {                                   \
        __syncthreads();                                                        \
        _Pragma("unroll") for (int i = 0; i < 4; ++i) {                         \
            int c = wave * 256 + i * 64 + lane;                                 \
            int row = c >> 3, c8 = c & 7;                                       \
            int sc = ((c8 ^ (row & 7)) << 3);                                   \
            GLOAD((Aptr) + (size_t)(rowBase + row) * (lda) + k0 + sc,           \
                  &As[(wave * 256 + i * 64) * 8]);                              \
            GLOAD((Bptr) + (size_t)(colBase + row) * (ldb) + k0 + sc,           \
                  &Bs[(wave * 256 + i * 64) * 8]);                              \
        }                                                                       \
        __syncthreads();                                                        \
        _Pragma("unroll") for (int kk = 0; kk < 2; ++kk) {                      \
            half8 af[4], bf[4];                                                 \
            _Pragma("unroll") for (int s = 0; s < 4; ++s) {                     \
                int rm = wr + s * 16 + l15;                                     \
                af[s] = *(const half8*)&As[rm * 64 +                            \
                        (((kk * 4 + quad) ^ (rm & 7)) << 3)];                   \
                int rn = wc + s * 16 + l15;                                     \
                bf[s] = *(const half8*)&Bs[rn * 64 +                            \
                        (((kk * 4 + quad) ^ (rn & 7)) << 3)];                   \
            }                                                                   \
            _Pragma("unroll") for (int sm = 0; sm < 4; ++sm)                    \
                _Pragma("unroll") for (int sn = 0; sn < 4; ++sn)                \
                    acc[sm][sn] = __builtin_amdgcn_mfma_f32_16x16x32_f16(       \
                        af[sm], bf[sn], acc[sm][sn], 0, 0, 0);                  \
        }                                                                       \
    }

// QKV: A = xh [4096][1024], B = Wt [3072][1024]. grid (32, 24).
// Q output is pre-scaled by 0.125*log2(e) so attention runs in exp2 domain.
__global__ __launch_bounds__(256) void qkv_gemm_kernel(
    const _Float16* __restrict__ xh, const _Float16* __restrict__ Wt,
    const float* __restrict__ bq, const float* __restrict__ bk, const float* __restrict__ bv,
    _Float16* __restrict__ qh, _Float16* __restrict__ kh, _Float16* __restrict__ vt)
{
    GEMM_MAIN(xh, Wt, 1024, 1024, 1024)

    const int m = colBase >> 10;            // 0=Q,1=K,2=V
    const int nIn = colBase & 1023;
    const float* __restrict__ bias = (m == 0) ? bq : (m == 1) ? bk : bv;
    const float sc_ = (m == 0) ? 0.18033688f : 1.0f;   // 0.125 * log2(e)

    if (m < 2) {
        _Float16* __restrict__ out = (m == 0) ? qh : kh;
#pragma unroll
        for (int sn = 0; sn < 4; ++sn) {
            int n = nIn + wc + sn * 16 + l15;
            int hh = n >> 6, e = n & 63;
            float bv_ = bias[n];
#pragma unroll
            for (int sm = 0; sm < 4; ++sm)
#pragma unroll
                for (int reg = 0; reg < 4; ++reg) {
                    int t = rowBase + wr + sm * 16 + quad * 4 + reg;
                    int bb = t >> 11, tt = t & (TT - 1);
                    out[(((size_t)bb * HH + hh) * TT + tt) * DH + e] =
                        (_Float16)((acc[sm][sn][reg] + bv_) * sc_);
                }
        }
    } else {
#pragma unroll
        for (int sn = 0; sn < 4; ++sn) {
            int n = nIn + wc + sn * 16 + l15;
            int hh = n >> 6, e = n & 63;
            float bv_ = bias[n];
#pragma unroll
            for (int sm = 0; sm < 4; ++sm) {
                int t = rowBase + wr + sm * 16 + quad * 4;
                int bb = t >> 11, tt = t & (TT - 1);
                int tile = tt >> 6, tp = tt & 63;
                half4v o;
#pragma unroll
                for (int reg = 0; reg < 4; ++reg)
                    o[reg] = (_Float16)(acc[sm][sn][reg] + bv_);
                *(half4v*)&vt[(((size_t)bb * HH + hh) * 32 + tile) * 4096 +
                              (size_t)e * 64 + tp] = o;
            }
        }
    }
}

// ---------------------------------------------------------------------------
// out-proj v2: 64x128 tile, grid (64,8)=512 blocks, 24 KB LDS -> ~6 blocks/CU
// (short K-loop needs block-level latency hiding, not bigger tiles).
// ---------------------------------------------------------------------------
__global__ __launch_bounds__(256) void out_gemm_kernel(
    const _Float16* __restrict__ zh, const _Float16* __restrict__ Wot,
    const float* __restrict__ bo, float* __restrict__ out)
{
    __shared__ _Float16 As[64 * 64];
    __shared__ _Float16 Bs[128 * 64];
    const int tid = threadIdx.x;
    const int wave = tid >> 6, lane = tid & 63;
    const int quad = lane >> 4, l15 = lane & 15;
    const int rowBase = blockIdx.x * 64;
    const int colBase = blockIdx.y * 128;
    const int wr = (wave >> 1) * 32, wc = (wave & 1) * 64;

    f32x4 acc[2][4];
#pragma unroll
    for (int sm = 0; sm < 2; ++sm)
#pragma unroll
        for (int sn = 0; sn < 4; ++sn) acc[sm][sn] = f32x4{0.f, 0.f, 0.f, 0.f};

    for (int k0 = 0; k0 < 1024; k0 += 64) {
        __syncthreads();
#pragma unroll
        for (int i = 0; i < 2; ++i) {
            int c = i * 256 + tid;
            int row = c >> 3, c8 = c & 7;
            GLOAD(zh + (size_t)(rowBase + row) * 1024 + k0 + ((c8 ^ (row & 7)) << 3),
                  &As[(i * 256 + wave * 64) * 8]);
        }
#pragma unroll
        for (int i = 0; i < 4; ++i) {
            int c = i * 256 + tid;
            int row = c >> 3, c8 = c & 7;
            GLOAD(Wot + (size_t)(colBase + row) * 1024 + k0 + ((c8 ^ (row & 7)) << 3),
                  &Bs[(i * 256 + wave * 64) * 8]);
        }
        __syncthreads();
#pragma unroll
        for (int kk = 0; kk < 2; ++kk) {
            half8 af[2], bf[4];
#pragma unroll
            for (int s = 0; s < 2; ++s) {
                int rm = wr + s * 16 + l15;
                af[s] = *(const half8*)&As[rm * 64 + (((kk * 4 + quad) ^ (rm & 7)) << 3)];
            }
#pragma unroll
            for (int s = 0; s < 4; ++s) {
                int rn = wc + s * 16 + l15;
                bf[s] = *(const half8*)&Bs[rn * 64 + (((kk * 4 + quad) ^ (rn & 7)) << 3)];
            }
#pragma unroll
            for (int sm = 0; sm < 2; ++sm)
#pragma unroll
                for (int sn = 0; sn < 4; ++sn)
                    acc[sm][sn] = __builtin_amdgcn_mfma_f32_16x16x32_f16(
                        af[sm], bf[sn], acc[sm][sn], 0, 0, 0);
        }
    }

#pragma unroll
    for (int sn = 0; sn < 4; ++sn) {
        int d = colBase + wc + sn * 16 + l15;
        float b_ = bo[d];
#pragma unroll
        for (int sm = 0; sm < 2; ++sm)
#pragma unroll
            for (int reg = 0; reg < 4; ++reg) {
                int r = rowBase + wr + sm * 16 + quad * 4 + reg;
                out[(size_t)r * 1024 + d] = acc[sm][sn][reg] + b_;
            }
    }
}

// ---------------------------------------------------------------------------
// Causal flash attention v3: fp16 MFMA, 256 threads (4 waves), 2 blocks/CU.
//  - q-tile 64 rows; wave owns 16 rows. Intra-block pairing: phase 0 does
//    q-tile (31-bx), phase 1 does q-tile bx -> every block exactly 33
//    k-tile-iters regardless of dispatch order. grid (16,16,2)=512 = 2/CU.
//  - double-buffered K/V via global_load_lds; 1 barrier per k-iter.
//  - exp2-domain softmax (Q pre-scaled by 0.125*log2e); no masked-tile guard
//    needed (underflow of exp2(-1e30 - m) handles it).
//  - row-sum via MFMA-by-ones.
// LDS: qs 8K | ks 2x8K | vs 2x8K | ps 9K = 49 KB -> 2 blocks/CU by grid.
// ---------------------------------------------------------------------------
#define ATTN_LDS (8192 + 16384 + 16384 + 9216)

__global__ __launch_bounds__(256) void attn_kernel(
    const _Float16* __restrict__ qh, const _Float16* __restrict__ kh,
    const _Float16* __restrict__ vt, _Float16* __restrict__ zh)
{
    __shared__ __align__(16) char smem[ATTN_LDS];
    _Float16* qs = (_Float16*)smem;                    // [64][64] swizzled
    _Float16* ks = (_Float16*)(smem + 8192);           // [2][64][64] swizzled
    _Float16* vs = (_Float16*)(smem + 24576);          // [2][64][64] swizzled
    _Float16* ps = (_Float16*)(smem + 40960);          // [64][72] padded

    const int tid  = threadIdx.x;
    const int wave = tid >> 6;
    const int lane = tid & 63;
    const int quad = lane >> 4;
    const int l15  = lane & 15;
    const int bx = blockIdx.x;         // 0..15
    const int h = blockIdx.y;
    const int b = blockIdx.z;

    const size_t headBase = ((size_t)b * HH + h) * (size_t)(TT * DH);
    const _Float16* kp  = kh + headBase;
    const _Float16* vtp = vt + ((size_t)b * HH + h) * 32 * 4096;

    half8 ones;
#pragma unroll
    for (int i = 0; i < 8; ++i) ones[i] = (_Float16)1.0f;

    auto stage_kv = [&](int s) {
        const int par = s & 1;
#pragma unroll
        for (int it = 0; it < 2; ++it) {
            int c = it * 256 + tid;
            int row = c >> 3, c8 = c & 7;
            size_t off = (size_t)s * 4096 + row * 64 + ((c8 ^ (row & 7)) << 3);
            GLOAD(kp + off,  &ks[par * 4096 + (it * 256 + wave * 64) * 8]);
            GLOAD(vtp + off, &vs[par * 4096 + (it * 256 + wave * 64) * 8]);
        }
    };

    for (int ph = 0; ph < 2; ++ph) {
        const int q32 = (ph == 0) ? (31 - bx) : bx;
        const int Q0 = q32 * 64;
        const int nk = q32 + 1;
        const _Float16* qp = qh + headBase + (size_t)Q0 * 64;

        __syncthreads();   // protect smem reuse across phases

        // stage Q (8 KB) + first K/V tile
#pragma unroll
        for (int it = 0; it < 2; ++it) {
            int c = it * 256 + tid;
            int row = c >> 3, c8 = c & 7;
            GLOAD(qp + (size_t)row * 64 + ((c8 ^ (row & 7)) << 3),
                  &qs[(it * 256 + wave * 64) * 8]);
        }
        stage_kv(0);
        __syncthreads();

        // hoisted Q A-frags (wave's 16 rows)
        const int rmq = wave * 16 + l15;
        const int swq = rmq & 7;
        half8 aq0 = *(const half8*)&qs[rmq * 64 + ((quad ^ swq) << 3)];
        half8 aq1 = *(const half8*)&qs[rmq * 64 + (((4 + quad) ^ swq) << 3)];

        f32x4 accO[4];
        float mrow[4], lsum[4];
#pragma unroll
        for (int j = 0; j < 4; ++j) {
            accO[j] = f32x4{0.f, 0.f, 0.f, 0.f};
            mrow[j] = -1e30f;
            lsum[j] = 0.f;
        }

        for (int s = 0; s < nk; ++s) {
            if (s + 1 < nk) stage_kv(s + 1);

            const _Float16* curK = &ks[(s & 1) * 4096];
            const _Float16* curV = &vs[(s & 1) * 4096];

            // S = Q K^T
            f32x4 S[4];
#pragma unroll
            for (int j = 0; j < 4; ++j) {
                int rn = j * 16 + l15, sw = rn & 7;
                half8 b0 = *(const half8*)&curK[rn * 64 + ((quad ^ sw) << 3)];
                half8 b1 = *(const half8*)&curK[rn * 64 + (((4 + quad) ^ sw) << 3)];
                f32x4 a = f32x4{0.f, 0.f, 0.f, 0.f};
                a = __builtin_amdgcn_mfma_f32_16x16x32_f16(aq0, b0, a, 0, 0, 0);
                a = __builtin_amdgcn_mfma_f32_16x16x32_f16(aq1, b1, a, 0, 0, 0);
                S[j] = a;
            }

            // causal mask: only the last tile is diagonal
            if (s == nk - 1) {
#pragma unroll
                for (int j = 0; j < 4; ++j) {
                    int col = j * 16 + l15;
#pragma unroll
                    for (int reg = 0; reg < 4; ++reg)
                        if (col > wave * 16 + quad * 4 + reg) S[j][reg] = -1e30f;
                }
            }

            // online softmax (exp2 domain)
#pragma unroll
            for (int reg = 0; reg < 4; ++reg) {
                float mt = fmaxf(fmaxf(S[0][reg], S[1][reg]),
                                 fmaxf(S[2][reg], S[3][reg]));
                mt = fmaxf(mt, __shfl_xor(mt, 1));
                mt = fmaxf(mt, __shfl_xor(mt, 2));
                mt = fmaxf(mt, __shfl_xor(mt, 4));
                mt = fmaxf(mt, __shfl_xor(mt, 8));
                float mnew = fmaxf(mrow[reg], mt);
                float alpha = exp2f(mrow[reg] - mnew);
                mrow[reg] = mnew;
                lsum[reg] *= alpha;
#pragma unroll
                for (int j = 0; j < 4; ++j) {
                    S[j][reg] = exp2f(S[j][reg] - mnew);
                    accO[j][reg] *= alpha;
                }
            }

            // P: C-layout -> LDS -> A-layout (wave-private strip)
            const int prow = wave * 16 + quad * 4;
#pragma unroll
            for (int j = 0; j < 4; ++j)
#pragma unroll
                for (int reg = 0; reg < 4; ++reg)
                    ps[(prow + reg) * 72 + j * 16 + l15] = (_Float16)S[j][reg];

            half8 ap0 = *(const half8*)&ps[rmq * 72 + quad * 8];
            half8 ap1 = *(const half8*)&ps[rmq * 72 + 32 + quad * 8];

            // row-sum via MFMA-by-ones
            {
                f32x4 psum = f32x4{0.f, 0.f, 0.f, 0.f};
                psum = __builtin_amdgcn_mfma_f32_16x16x32_f16(ap0, ones, psum, 0, 0, 0);
                psum = __builtin_amdgcn_mfma_f32_16x16x32_f16(ap1, ones, psum, 0, 0, 0);
#pragma unroll
                for (int reg = 0; reg < 4; ++reg) lsum[reg] += psum[reg];
            }

            // O += P V
#pragma unroll
            for (int j = 0; j < 4; ++j) {
                int rn = j * 16 + l15, sw = rn & 7;
                half8 bv0 = *(const half8*)&curV[rn * 64 + ((quad ^ sw) << 3)];
                half8 bv1 = *(const half8*)&curV[rn * 64 + (((4 + quad) ^ sw) << 3)];
                accO[j] = __builtin_amdgcn_mfma_f32_16x16x32_f16(ap0, bv0, accO[j], 0, 0, 0);
                accO[j] = __builtin_amdgcn_mfma_f32_16x16x32_f16(ap1, bv1, accO[j], 0, 0, 0);
            }

            __syncthreads();   // drains prefetch; protects parity buffer reuse
        }

        // epilogue
#pragma unroll
        for (int reg = 0; reg < 4; ++reg) {
            float inv = 1.f / lsum[reg];
            int t = Q0 + wave * 16 + quad * 4 + reg;
            size_t rowOff = ((size_t)b * TT + t) * DD + h * DH;
#pragma unroll
            for (int j = 0; j < 4; ++j)
                zh[rowOff + j * 16 + l15] = (_Float16)(accO[j][reg] * inv);
        }
    }
}

extern "C" void kernel_launch(void* const* d_in, const int* in_sizes, int n_in,
                              void* d_out, int out_size, void* d_ws, size_t ws_size,
                              hipStream_t stream) {
    const float* x  = (const float*)d_in[0];
    const float* Wq = (const float*)d_in[1];
    const float* Wk = (const float*)d_in[2];
    const float* Wv = (const float*)d_in[3];
    const float* Wo = (const float*)d_in[4];
    const float* bq = (const float*)d_in[5];
    const float* bk = (const float*)d_in[6];
    const float* bv = (const float*)d_in[7];
    const float* bo = (const float*)d_in[8];
    float* out = (float*)d_out;

    const size_t MB = 1u << 20;
    char* wsb = (char*)d_ws;
    _Float16* xh  = (_Float16*)(wsb + 0 * MB);    //  8 MB  [4096][1024]
    _Float16* Wt  = (_Float16*)(wsb + 8 * MB);    //  6 MB  [3072][1024]
    _Float16* Wot = (_Float16*)(wsb + 14 * MB);   //  2 MB  [1024][1024]
    _Float16* qh  = (_Float16*)(wsb + 16 * MB);   //  8 MB  [b][h][t][e] (pre-scaled, exp2 domain)
    _Float16* kh  = (_Float16*)(wsb + 24 * MB);   //  8 MB
    _Float16* vt  = (_Float16*)(wsb + 32 * MB);   //  8 MB  [b][h][tile][e][t']
    _Float16* zh  = (_Float16*)(wsb + 40 * MB);   //  8 MB  [4096][1024]

    cvt_all_kernel<<<3072, 256, 0, stream>>>(x, Wq, Wk, Wv, Wo, xh, Wt, Wot);
    qkv_gemm_kernel<<<dim3(32, 24), 256, 0, stream>>>(xh, Wt, bq, bk, bv, qh, kh, vt);
    attn_kernel<<<dim3(16, HH, BB), 256, 0, stream>>>(qh, kh, vt, zh);
    out_gemm_kernel<<<dim3(64, 8), 256, 0, stream>>>(zh, Wot, bo, out);
}